// Round 19
// baseline (145.745 us; speedup 1.0000x reference)
//
#include <hip/hip_runtime.h>

// FuncConv: out = select(inv, mlp_inv(res), res); res = mlp_and(mean_dst(msg));
// msg = select(r, mlp_inv(feat[src]), feat[src]).
// R17: remove the chist memset dispatch. prep_hist now writes per-block
// partial histograms (plain stores, no global atomics, no pre-zero); cscan
// sums the <=256 partial rows per bucket before scanning. All other kernel
// bodies byte-identical to R16 (passed).
// Chain: prep_hist -> cscan -> {coarse_bin || pass1} -> fine -> gather -> mlp45.
//
// ws: featb[N*H bf16] invb[N*H bf16] neighb[N*H bf16]
//     offsets[N+1] ebuf[E] packed[E] frg[80*512 us] pbh[256*256] cbase[257] ccur[256]

#define H 128
#define HH 64
#define BSH 9     // log2 nodes per coarse bucket
#define BSZ 512   // nodes per coarse bucket
#define ACH 4096  // edges per coarse block

typedef float f32x4 __attribute__((ext_vector_type(4)));
typedef __bf16 bf16x8 __attribute__((ext_vector_type(8)));
typedef unsigned short us8 __attribute__((ext_vector_type(8)));
typedef unsigned short ushort_t;

__device__ __forceinline__ unsigned short bfbits(float f) {
    __bf16 h = (__bf16)f;                       // RNE convert
    return __builtin_bit_cast(unsigned short, h);
}
__device__ __forceinline__ bf16x8 as_bf16x8(us8 v) {
    return __builtin_bit_cast(bf16x8, v);
}
__device__ __forceinline__ float bfl(unsigned short u) {
    return __builtin_bit_cast(float, ((unsigned)u) << 16);
}

// transpose buffers, XOR-swizzled (byte ^= (row&7)<<4; 16B groups)
__device__ __forceinline__ int tb_off(int m, int j) {      // 16 x 64 bf16
    return m * 64 + ((((j * 2) ^ ((m & 7) << 4))) >> 1);
}
__device__ __forceinline__ int tb2_off(int m, int j) {     // 16 x 128 bf16
    return m * 128 + ((((j * 2) ^ ((m & 7) << 4))) >> 1);
}
__device__ __forceinline__ bf16x8 ld_tb(const unsigned short* tb, int m, int j0) {
    return as_bf16x8(*(const us8*)&tb[tb_off(m, j0)]);
}
__device__ __forceinline__ bf16x8 ld_tb2(const unsigned short* tb, int m, int j0) {
    return as_bf16x8(*(const us8*)&tb[tb2_off(m, j0)]);
}
// weight B-fragment from global (L1/L2-hot, 40KB working set per MLP)
__device__ __forceinline__ bf16x8 ld_frg(const ushort_t* __restrict__ FRG, int fid, int lane) {
    return as_bf16x8(*(const us8*)&FRG[(fid * 64 + lane) * 8]);
}

// ---------------- coarse dst-histogram (per-block partials) || frag pre-pack --
__global__ __launch_bounds__(256) void prep_hist_k(
    const int* __restrict__ dst, int* __restrict__ pbh,
    const float* __restrict__ iw1, const float* __restrict__ iw2,
    const float* __restrict__ iw3,
    const float* __restrict__ aw1, const float* __restrict__ aw2,
    const float* __restrict__ aw3,
    ushort_t* __restrict__ frg, int E, int cgrid)
{
    __shared__ int h[256];
    const int tid = threadIdx.x;
    if (blockIdx.x < cgrid) {
        h[tid] = 0;
        __syncthreads();
        const int base = blockIdx.x * ACH;
#pragma unroll
        for (int j = 0; j < 16; ++j) {
            const int e = base + j * 256 + tid;
            if (e < E) atomicAdd(&h[dst[e] >> BSH], 1);
        }
        __syncthreads();
        pbh[blockIdx.x * 256 + tid] = h[tid];     // plain store, no pre-zero
    } else {
        const int g = (blockIdx.x - cgrid) * 256 + tid;     // 80*64 = 5120
        const int fid2 = g >> 6;
        if (fid2 >= 80) return;
        const int lane = g & 63;
        const int ln = lane & 15, hi = lane >> 4;
        const int set = fid2 / 40;
        const int fid = fid2 - set * 40;
        const float* w; int inF, s, t;
        if (fid < 16)      { w = set ? aw1 : iw1; inF = H;  s = fid >> 2;        t = fid & 3; }
        else if (fid < 24) { w = set ? aw2 : iw2; inF = HH; s = (fid - 16) >> 2; t = (fid - 16) & 3; }
        else               { w = set ? aw3 : iw3; inF = HH; s = (fid - 24) >> 3; t = (fid - 24) & 7; }
        const float* p = w + (size_t)(t * 16 + ln) * inF + (s * 32 + hi * 8);
        f32x4 a = *(const f32x4*)p;
        f32x4 b = *(const f32x4*)(p + 4);
        ushort_t* d = &frg[(size_t)(fid2 * 64 + lane) * 8];
        d[0] = bfbits(a[0]); d[1] = bfbits(a[1]); d[2] = bfbits(a[2]); d[3] = bfbits(a[3]);
        d[4] = bfbits(b[0]); d[5] = bfbits(b[1]); d[6] = bfbits(b[2]); d[7] = bfbits(b[3]);
    }
}

// single block: sum partial hists per bucket, then exclusive scan -> cbase/ccur
__global__ __launch_bounds__(256) void cscan_k(
    const int* __restrict__ pbh, int* __restrict__ cbase, int* __restrict__ ccur,
    int nb, int E, int cgrid)
{
    __shared__ int s[256];
    const int tid = threadIdx.x;
    int v = 0;
    for (int b = 0; b < cgrid; ++b) v += pbh[b * 256 + tid];
    if (tid >= nb) v = 0;
    s[tid] = v;
    __syncthreads();
    for (int st = 1; st < 256; st <<= 1) {
        int t = (tid >= st) ? s[tid - st] : 0;
        __syncthreads();
        s[tid] += t;
        __syncthreads();
    }
    const int excl = s[tid] - v;
    if (tid < nb) { cbase[tid] = excl; ccur[tid] = excl; }
    if (tid == 0) cbase[nb] = E;
}

// ---------------- fused: coarse bin || MLP pass 1 (bodies = R16) --------------
__global__ __launch_bounds__(256) void binp1_k(
    const int* __restrict__ src, const int* __restrict__ dst,
    const int* __restrict__ r,
    int* __restrict__ ccur, unsigned* __restrict__ ebuf,
    const float* __restrict__ X,
    const ushort_t* __restrict__ FRG,
    const float* __restrict__ B1, const float* __restrict__ B2,
    const float* __restrict__ B3,
    ushort_t* __restrict__ invb, ushort_t* __restrict__ featb,
    int E, int N, int cgrid, int ntiles)
{
    __shared__ __align__(16) unsigned short TBs[4 * 2 * 16 * 64];  // 16 KB
    const int tid = threadIdx.x;

    if (blockIdx.x < cgrid) {
        int* hcnt  = (int*)TBs;           // 256
        int* gbase = hcnt + 256;          // 256
        int* lcur  = gbase + 256;         // 256
        hcnt[tid] = 0;
        __syncthreads();
        const int base = blockIdx.x * ACH;
        unsigned v[16]; int bk[16];
#pragma unroll
        for (int j = 0; j < 16; ++j) {
            const int e = base + j * 256 + tid;
            if (e < E) {
                const int d = dst[e];
                bk[j] = d >> BSH;
                v[j] = ((unsigned)(d & (BSZ - 1)) << 18) |
                       ((unsigned)src[e] << 1) | (unsigned)r[e];
                atomicAdd(&hcnt[bk[j]], 1);
            } else bk[j] = -1;
        }
        __syncthreads();
        const int c = hcnt[tid];
        gbase[tid] = (c > 0) ? atomicAdd(&ccur[tid], c) : 0;
        lcur[tid] = 0;
        __syncthreads();
#pragma unroll
        for (int j = 0; j < 16; ++j) {
            if (bk[j] >= 0) {
                const int loc = atomicAdd(&lcur[bk[j]], 1);
                ebuf[gbase[bk[j]] + loc] = v[j];
            }
        }
        return;
    }

    // ------- MLP pass-1 body: 4 waves x 2 tiles, shared frag loads -----------
    const int wv   = tid >> 6;
    const int lane = tid & 63;
    const int ln   = lane & 15;
    const int hi   = lane >> 4;

    const int gw = (blockIdx.x - cgrid) * 4 + wv;
    const int t0 = gw * 2;
    if (t0 >= ntiles) return;
    const bool hasB = (t0 + 1) < ntiles;
    const int node0A = t0 * 16;
    const int node0B = hasB ? (t0 + 1) * 16 : node0A;

    float b1r[4], b2r[4], b3r[8];
#pragma unroll
    for (int t = 0; t < 4; ++t) b1r[t] = B1[t * 16 + ln];
#pragma unroll
    for (int t = 0; t < 4; ++t) b2r[t] = B2[t * 16 + ln];
#pragma unroll
    for (int t = 0; t < 8; ++t) b3r[t] = B3[t * 16 + ln];

    unsigned short* tbA = &TBs[(wv * 2) * 16 * 64];
    unsigned short* tbB = tbA + 16 * 64;

    const size_t roA = (size_t)min(node0A + ln, N - 1) * H;
    const size_t roB = (size_t)min(node0B + ln, N - 1) * H;

    bf16x8 aA[4], aB[4];
#pragma unroll
    for (int s = 0; s < 4; ++s) {
        {
            f32x4 u = *(const f32x4*)(X + roA + s * 32 + hi * 8);
            f32x4 v = *(const f32x4*)(X + roA + s * 32 + hi * 8 + 4);
            bf16x8 f;
            f[0] = (__bf16)u[0]; f[1] = (__bf16)u[1]; f[2] = (__bf16)u[2]; f[3] = (__bf16)u[3];
            f[4] = (__bf16)v[0]; f[5] = (__bf16)v[1]; f[6] = (__bf16)v[2]; f[7] = (__bf16)v[3];
            aA[s] = f;
            *(us8*)(featb + roA + s * 32 + hi * 8) = __builtin_bit_cast(us8, f);
        }
        {
            f32x4 u = *(const f32x4*)(X + roB + s * 32 + hi * 8);
            f32x4 v = *(const f32x4*)(X + roB + s * 32 + hi * 8 + 4);
            bf16x8 f;
            f[0] = (__bf16)u[0]; f[1] = (__bf16)u[1]; f[2] = (__bf16)u[2]; f[3] = (__bf16)u[3];
            f[4] = (__bf16)v[0]; f[5] = (__bf16)v[1]; f[6] = (__bf16)v[2]; f[7] = (__bf16)v[3];
            aB[s] = f;
            if (hasB) *(us8*)(featb + roB + s * 32 + hi * 8) = __builtin_bit_cast(us8, f);
        }
    }

#pragma unroll 4
    for (int t = 0; t < 4; ++t) {
        f32x4 accA = {0.f, 0.f, 0.f, 0.f}, accB = {0.f, 0.f, 0.f, 0.f};
#pragma unroll
        for (int s = 0; s < 4; ++s) {
            const bf16x8 f = ld_frg(FRG, s * 4 + t, lane);
            accA = __builtin_amdgcn_mfma_f32_16x16x32_bf16(aA[s], f, accA, 0, 0, 0);
            accB = __builtin_amdgcn_mfma_f32_16x16x32_bf16(aB[s], f, accB, 0, 0, 0);
        }
#pragma unroll
        for (int q = 0; q < 4; ++q) {
            float yA = accA[q] + b1r[t];
            yA = (yA >= 0.f) ? yA : 0.01f * yA;
            tbA[tb_off(hi * 4 + q, t * 16 + ln)] = bfbits(yA);
            float yB = accB[q] + b1r[t];
            yB = (yB >= 0.f) ? yB : 0.01f * yB;
            tbB[tb_off(hi * 4 + q, t * 16 + ln)] = bfbits(yB);
        }
    }

    bf16x8 a2A[2], a2B[2];
#pragma unroll
    for (int s = 0; s < 2; ++s) {
        a2A[s] = ld_tb(tbA, ln, s * 32 + hi * 8);
        a2B[s] = ld_tb(tbB, ln, s * 32 + hi * 8);
    }
#pragma unroll 4
    for (int t = 0; t < 4; ++t) {
        f32x4 accA = {0.f, 0.f, 0.f, 0.f}, accB = {0.f, 0.f, 0.f, 0.f};
#pragma unroll
        for (int s = 0; s < 2; ++s) {
            const bf16x8 f = ld_frg(FRG, 16 + s * 4 + t, lane);
            accA = __builtin_amdgcn_mfma_f32_16x16x32_bf16(a2A[s], f, accA, 0, 0, 0);
            accB = __builtin_amdgcn_mfma_f32_16x16x32_bf16(a2B[s], f, accB, 0, 0, 0);
        }
#pragma unroll
        for (int q = 0; q < 4; ++q) {
            float yA = accA[q] + b2r[t];
            yA = (yA >= 0.f) ? yA : 0.01f * yA;
            tbA[tb_off(hi * 4 + q, t * 16 + ln)] = bfbits(yA);
            float yB = accB[q] + b2r[t];
            yB = (yB >= 0.f) ? yB : 0.01f * yB;
            tbB[tb_off(hi * 4 + q, t * 16 + ln)] = bfbits(yB);
        }
    }

    bf16x8 a3A[2], a3B[2];
#pragma unroll
    for (int s = 0; s < 2; ++s) {
        a3A[s] = ld_tb(tbA, ln, s * 32 + hi * 8);
        a3B[s] = ld_tb(tbB, ln, s * 32 + hi * 8);
    }
#pragma unroll
    for (int half = 0; half < 2; ++half) {
#pragma unroll 2
        for (int t2 = 0; t2 < 4; ++t2) {
            const int t = half * 4 + t2;
            f32x4 accA = {0.f, 0.f, 0.f, 0.f}, accB = {0.f, 0.f, 0.f, 0.f};
#pragma unroll
            for (int s = 0; s < 2; ++s) {
                const bf16x8 f = ld_frg(FRG, 24 + s * 8 + t, lane);
                accA = __builtin_amdgcn_mfma_f32_16x16x32_bf16(a3A[s], f, accA, 0, 0, 0);
                accB = __builtin_amdgcn_mfma_f32_16x16x32_bf16(a3B[s], f, accB, 0, 0, 0);
            }
#pragma unroll
            for (int q = 0; q < 4; ++q) {
                tbA[tb_off(hi * 4 + q, t2 * 16 + ln)] = bfbits(accA[q] + b3r[t]);
                tbB[tb_off(hi * 4 + q, t2 * 16 + ln)] = bfbits(accB[q] + b3r[t]);
            }
        }
        const int rr = lane >> 2, c0 = (lane & 3) * 16;
        if (node0A + rr < N) {
            us8 w0 = __builtin_bit_cast(us8, ld_tb(tbA, rr, c0));
            us8 w1 = __builtin_bit_cast(us8, ld_tb(tbA, rr, c0 + 8));
            ushort_t* op = invb + (size_t)(node0A + rr) * H + half * 64 + c0;
            *(us8*)op = w0;
            *(us8*)(op + 8) = w1;
        }
        if (hasB && node0B + rr < N) {
            us8 w0 = __builtin_bit_cast(us8, ld_tb(tbB, rr, c0));
            us8 w1 = __builtin_bit_cast(us8, ld_tb(tbB, rr, c0 + 8));
            ushort_t* op = invb + (size_t)(node0B + rr) * H + half * 64 + c0;
            *(us8*)op = w0;
            *(us8*)(op + 8) = w1;
        }
    }
}

// ---------------- fine CSR build (standalone, 256 thr, pair-scan) -------------
__global__ __launch_bounds__(256) void fine_k(
    const unsigned* __restrict__ ebuf, const int* __restrict__ cbase,
    int* __restrict__ offsets, int* __restrict__ packed, int N, int E, int NB)
{
    __shared__ int lcur[BSZ];
    __shared__ int ps[256];
    const int tid = threadIdx.x;
    const int b = blockIdx.x;
    const int lo = b << BSH;
    const int nn = min(BSZ, N - lo);
    const int rstart = cbase[b];
    const int rend   = cbase[b + 1];
    lcur[tid] = 0; lcur[tid + 256] = 0;
    __syncthreads();
    for (int i = rstart + tid; i < rend; i += 256)
        atomicAdd(&lcur[ebuf[i] >> 18], 1);
    __syncthreads();
    const int v0 = lcur[2 * tid];
    const int v1 = lcur[2 * tid + 1];
    const int psum = v0 + v1;
    ps[tid] = psum;
    __syncthreads();
    for (int st = 1; st < 256; st <<= 1) {
        int t = (tid >= st) ? ps[tid - st] : 0;
        __syncthreads();
        ps[tid] += t;
        __syncthreads();
    }
    const int e0 = rstart + ps[tid] - psum;     // exclusive prefix
    const int e1 = e0 + v0;
    if (2 * tid < nn)     offsets[lo + 2 * tid] = e0;
    if (2 * tid + 1 < nn) offsets[lo + 2 * tid + 1] = e1;
    if (b == NB - 1 && tid == 0) offsets[N] = E;
    __syncthreads();
    lcur[2 * tid] = e0;
    lcur[2 * tid + 1] = e1;
    __syncthreads();
    for (int i = rstart + tid; i < rend; i += 256) {
        const unsigned w = ebuf[i];
        const int dloc = w >> 18;
        const int pos = atomicAdd(&lcur[dloc], 1);
        packed[pos] = (int)(((w & 0x3ffffu) >> 1) | ((w & 1u) << 31));
    }
}

// 4 nodes per wave (16 lanes each = full 128-col row); 8-deep edge unroll (R12)
__global__ __launch_bounds__(256) void gather_mean_k(
    const ushort_t* __restrict__ featb, const ushort_t* __restrict__ invb,
    const int* __restrict__ offsets,
    const int* __restrict__ packed, ushort_t* __restrict__ neighb, int N)
{
    const int wv = threadIdx.x >> 6, lane = threadIdx.x & 63;
    const int n0 = (blockIdx.x * 4 + wv) * 4;
    if (n0 >= N) return;
    const int g = lane >> 4;                      // node-in-wave 0..3
    const int nid = n0 + g;
    const bool act = nid < N;
    const int n = min(nid, N - 1);
    const int start = offsets[n];
    const int d = offsets[n + 1] - start;
    const size_t co = (size_t)(lane & 15) * 8;    // col base (8 bf16 = 16B)
    float a[8] = {0.f, 0.f, 0.f, 0.f, 0.f, 0.f, 0.f, 0.f};
    int k = 0;
    for (; k + 7 < d; k += 8) {                   // 8 rows in flight
        int p[8];
#pragma unroll
        for (int j = 0; j < 8; ++j) p[j] = packed[start + k + j];
        us8 u[8];
#pragma unroll
        for (int j = 0; j < 8; ++j) {
            const ushort_t* t = (p[j] < 0) ? invb : featb;
            u[j] = *(const us8*)(t + (size_t)(p[j] & 0x7fffffff) * H + co);
        }
#pragma unroll
        for (int j = 0; j < 8; ++j)
#pragma unroll
            for (int i = 0; i < 8; ++i) a[i] += bfl(u[j][i]);
    }
    if (k + 3 < d) {                              // 4 rows in flight
        int p[4];
#pragma unroll
        for (int j = 0; j < 4; ++j) p[j] = packed[start + k + j];
        us8 u[4];
#pragma unroll
        for (int j = 0; j < 4; ++j) {
            const ushort_t* t = (p[j] < 0) ? invb : featb;
            u[j] = *(const us8*)(t + (size_t)(p[j] & 0x7fffffff) * H + co);
        }
#pragma unroll
        for (int j = 0; j < 4; ++j)
#pragma unroll
            for (int i = 0; i < 8; ++i) a[i] += bfl(u[j][i]);
        k += 4;
    }
    for (; k < d; ++k) {                          // <=3 rows tail
        const int p = packed[start + k];
        const ushort_t* t = (p < 0) ? invb : featb;
        const us8 u = *(const us8*)(t + (size_t)(p & 0x7fffffff) * H + co);
#pragma unroll
        for (int i = 0; i < 8; ++i) a[i] += bfl(u[i]);
    }
    if (act) {
        const float scl = 1.0f / (float)max(d, 1);
        us8 o;
#pragma unroll
        for (int i = 0; i < 8; ++i) o[i] = bfbits(a[i] * scl);
        *(us8*)(neighb + (size_t)n * H + co) = o;
    }
}

// ---------------- fused pass 4+5, 2 tiles per wave (R9/R12) -------------------
__global__ __launch_bounds__(256) void mlp45_k(
    const ushort_t* __restrict__ Xb,          // neighb, bf16
    const ushort_t* __restrict__ FRGa,        // and frags
    const ushort_t* __restrict__ FRGi,        // inv frags
    const float* __restrict__ A1, const float* __restrict__ A2,
    const float* __restrict__ A3,
    const float* __restrict__ I1, const float* __restrict__ I2,
    const float* __restrict__ I3,
    float* __restrict__ OUT,
    const int* __restrict__ invp,
    int nrows, int ntiles)
{
    __shared__ __align__(16) unsigned short TB2[4 * 2 * 16 * 128];  // 32 KB
    const int tid  = threadIdx.x;
    const int wv   = tid >> 6;
    const int lane = tid & 63;
    const int ln   = lane & 15;
    const int hi   = lane >> 4;

    const int gw = blockIdx.x * 4 + wv;
    const int t0 = gw * 2;
    if (t0 >= ntiles) return;
    const bool hasB = (t0 + 1) < ntiles;
    const int node0A = t0 * 16;
    const int node0B = hasB ? (t0 + 1) * 16 : node0A;

    unsigned short* tbA = &TB2[(wv * 2) * 16 * 128];
    unsigned short* tbB = tbA + 16 * 128;

    int iqA[4], iqB[4];
#pragma unroll
    for (int q = 0; q < 4; ++q) {
        const int rA = node0A + hi * 4 + q;
        const int rB = node0B + hi * 4 + q;
        iqA[q] = (rA < nrows) ? invp[rA] : 1;
        iqB[q] = (rB < nrows) ? invp[rB] : 1;
    }

    // ---- phase A: mlp_and ----
    {
        float b1r[4], b2r[4], b3r[8];
#pragma unroll
        for (int t = 0; t < 4; ++t) b1r[t] = A1[t * 16 + ln];
#pragma unroll
        for (int t = 0; t < 4; ++t) b2r[t] = A2[t * 16 + ln];
#pragma unroll
        for (int t = 0; t < 8; ++t) b3r[t] = A3[t * 16 + ln];

        const size_t roA = (size_t)min(node0A + ln, nrows - 1) * H;
        const size_t roB = (size_t)min(node0B + ln, nrows - 1) * H;
        bf16x8 aA[4], aB[4];
#pragma unroll
        for (int s = 0; s < 4; ++s) {
            aA[s] = as_bf16x8(*(const us8*)(Xb + roA + s * 32 + hi * 8));
            aB[s] = as_bf16x8(*(const us8*)(Xb + roB + s * 32 + hi * 8));
        }

#pragma unroll 2
        for (int t = 0; t < 4; ++t) {
            f32x4 accA = {0.f, 0.f, 0.f, 0.f}, accB = {0.f, 0.f, 0.f, 0.f};
#pragma unroll
            for (int s = 0; s < 4; ++s) {
                const bf16x8 f = ld_frg(FRGa, s * 4 + t, lane);
                accA = __builtin_amdgcn_mfma_f32_16x16x32_bf16(aA[s], f, accA, 0, 0, 0);
                accB = __builtin_amdgcn_mfma_f32_16x16x32_bf16(aB[s], f, accB, 0, 0, 0);
            }
#pragma unroll
            for (int q = 0; q < 4; ++q) {
                float yA = accA[q] + b1r[t];
                yA = (yA >= 0.f) ? yA : 0.01f * yA;
                tbA[tb2_off(hi * 4 + q, t * 16 + ln)] = bfbits(yA);
                float yB = accB[q] + b1r[t];
                yB = (yB >= 0.f) ? yB : 0.01f * yB;
                tbB[tb2_off(hi * 4 + q, t * 16 + ln)] = bfbits(yB);
            }
        }

        bf16x8 a2A[2], a2B[2];
#pragma unroll
        for (int s = 0; s < 2; ++s) {
            a2A[s] = ld_tb2(tbA, ln, s * 32 + hi * 8);
            a2B[s] = ld_tb2(tbB, ln, s * 32 + hi * 8);
        }
#pragma unroll 2
        for (int t = 0; t < 4; ++t) {
            f32x4 accA = {0.f, 0.f, 0.f, 0.f}, accB = {0.f, 0.f, 0.f, 0.f};
#pragma unroll
            for (int s = 0; s < 2; ++s) {
                const bf16x8 f = ld_frg(FRGa, 16 + s * 4 + t, lane);
                accA = __builtin_amdgcn_mfma_f32_16x16x32_bf16(a2A[s], f, accA, 0, 0, 0);
                accB = __builtin_amdgcn_mfma_f32_16x16x32_bf16(a2B[s], f, accB, 0, 0, 0);
            }
#pragma unroll
            for (int q = 0; q < 4; ++q) {
                float yA = accA[q] + b2r[t];
                yA = (yA >= 0.f) ? yA : 0.01f * yA;
                tbA[tb2_off(hi * 4 + q, t * 16 + ln)] = bfbits(yA);
                float yB = accB[q] + b2r[t];
                yB = (yB >= 0.f) ? yB : 0.01f * yB;
                tbB[tb2_off(hi * 4 + q, t * 16 + ln)] = bfbits(yB);
            }
        }

        bf16x8 a3A[2], a3B[2];
#pragma unroll
        for (int s = 0; s < 2; ++s) {
            a3A[s] = ld_tb2(tbA, ln, s * 32 + hi * 8);
            a3B[s] = ld_tb2(tbB, ln, s * 32 + hi * 8);
        }
#pragma unroll 2
        for (int t = 0; t < 8; ++t) {
            f32x4 accA = {0.f, 0.f, 0.f, 0.f}, accB = {0.f, 0.f, 0.f, 0.f};
#pragma unroll
            for (int s = 0; s < 2; ++s) {
                const bf16x8 f = ld_frg(FRGa, 24 + s * 8 + t, lane);
                accA = __builtin_amdgcn_mfma_f32_16x16x32_bf16(a3A[s], f, accA, 0, 0, 0);
                accB = __builtin_amdgcn_mfma_f32_16x16x32_bf16(a3B[s], f, accB, 0, 0, 0);
            }
#pragma unroll
            for (int q = 0; q < 4; ++q) {
                const float yA = accA[q] + b3r[t];
                tbA[tb2_off(hi * 4 + q, t * 16 + ln)] = bfbits(yA);
                const int rA = node0A + hi * 4 + q;
                if (rA < nrows && !iqA[q])
                    OUT[(size_t)rA * H + t * 16 + ln] = yA;
                const float yB = accB[q] + b3r[t];
                tbB[tb2_off(hi * 4 + q, t * 16 + ln)] = bfbits(yB);
                const int rB = node0B + hi * 4 + q;
                if (hasB && rB < nrows && !iqB[q])
                    OUT[(size_t)rB * H + t * 16 + ln] = yB;
            }
        }
    }

    // ---- phase B: mlp_inv(res) for inv rows ----
    {
        float b1r[4], b2r[4], b3r[8];
#pragma unroll
        for (int t = 0; t < 4; ++t) b1r[t] = I1[t * 16 + ln];
#pragma unroll
        for (int t = 0; t < 4; ++t) b2r[t] = I2[t * 16 + ln];
#pragma unroll
        for (int t = 0; t < 8; ++t) b3r[t] = I3[t * 16 + ln];

        bf16x8 aA[4], aB[4];
#pragma unroll
        for (int s = 0; s < 4; ++s) {
            aA[s] = ld_tb2(tbA, ln, s * 32 + hi * 8);   // reads drain before writes
            aB[s] = ld_tb2(tbB, ln, s * 32 + hi * 8);
        }

#pragma unroll 2
        for (int t = 0; t < 4; ++t) {
            f32x4 accA = {0.f, 0.f, 0.f, 0.f}, accB = {0.f, 0.f, 0.f, 0.f};
#pragma unroll
            for (int s = 0; s < 4; ++s) {
                const bf16x8 f = ld_frg(FRGi, s * 4 + t, lane);
                accA = __builtin_amdgcn_mfma_f32_16x16x32_bf16(aA[s], f, accA, 0, 0, 0);
                accB = __builtin_amdgcn_mfma_f32_16x16x32_bf16(aB[s], f, accB, 0, 0, 0);
            }
#pragma unroll
            for (int q = 0; q < 4; ++q) {
                float yA = accA[q] + b1r[t];
                yA = (yA >= 0.f) ? yA : 0.01f * yA;
                tbA[tb2_off(hi * 4 + q, t * 16 + ln)] = bfbits(yA);
                float yB = accB[q] + b1r[t];
                yB = (yB >= 0.f) ? yB : 0.01f * yB;
                tbB[tb2_off(hi * 4 + q, t * 16 + ln)] = bfbits(yB);
            }
        }

        bf16x8 a2A[2], a2B[2];
#pragma unroll
        for (int s = 0; s < 2; ++s) {
            a2A[s] = ld_tb2(tbA, ln, s * 32 + hi * 8);
            a2B[s] = ld_tb2(tbB, ln, s * 32 + hi * 8);
        }
#pragma unroll 2
        for (int t = 0; t < 4; ++t) {
            f32x4 accA = {0.f, 0.f, 0.f, 0.f}, accB = {0.f, 0.f, 0.f, 0.f};
#pragma unroll
            for (int s = 0; s < 2; ++s) {
                const bf16x8 f = ld_frg(FRGi, 16 + s * 4 + t, lane);
                accA = __builtin_amdgcn_mfma_f32_16x16x32_bf16(a2A[s], f, accA, 0, 0, 0);
                accB = __builtin_amdgcn_mfma_f32_16x16x32_bf16(a2B[s], f, accB, 0, 0, 0);
            }
#pragma unroll
            for (int q = 0; q < 4; ++q) {
                float yA = accA[q] + b2r[t];
                yA = (yA >= 0.f) ? yA : 0.01f * yA;
                tbA[tb2_off(hi * 4 + q, t * 16 + ln)] = bfbits(yA);
                float yB = accB[q] + b2r[t];
                yB = (yB >= 0.f) ? yB : 0.01f * yB;
                tbB[tb2_off(hi * 4 + q, t * 16 + ln)] = bfbits(yB);
            }
        }

        bf16x8 a3A[2], a3B[2];
#pragma unroll
        for (int s = 0; s < 2; ++s) {
            a3A[s] = ld_tb2(tbA, ln, s * 32 + hi * 8);
            a3B[s] = ld_tb2(tbB, ln, s * 32 + hi * 8);
        }
#pragma unroll 2
        for (int t = 0; t < 8; ++t) {
            f32x4 accA = {0.f, 0.f, 0.f, 0.f}, accB = {0.f, 0.f, 0.f, 0.f};
#pragma unroll
            for (int s = 0; s < 2; ++s) {
                const bf16x8 f = ld_frg(FRGi, 24 + s * 8 + t, lane);
                accA = __builtin_amdgcn_mfma_f32_16x16x32_bf16(a3A[s], f, accA, 0, 0, 0);
                accB = __builtin_amdgcn_mfma_f32_16x16x32_bf16(a3B[s], f, accB, 0, 0, 0);
            }
#pragma unroll
            for (int q = 0; q < 4; ++q) {
                const int rA = node0A + hi * 4 + q;
                if (rA < nrows && iqA[q])
                    OUT[(size_t)rA * H + t * 16 + ln] = accA[q] + b3r[t];
                const int rB = node0B + hi * 4 + q;
                if (hasB && rB < nrows && iqB[q])
                    OUT[(size_t)rB * H + t * 16 + ln] = accB[q] + b3r[t];
            }
        }
    }
}

extern "C" void kernel_launch(void* const* d_in, const int* in_sizes, int n_in,
                              void* d_out, int out_size, void* d_ws, size_t ws_size,
                              hipStream_t stream) {
    const float* feat = (const float*)d_in[0];
    const int*   src  = (const int*)d_in[1];
    const int*   dst  = (const int*)d_in[2];
    const int*   r    = (const int*)d_in[3];
    const int*   inv  = (const int*)d_in[4];
    const float* iw1 = (const float*)d_in[5],  *ib1 = (const float*)d_in[6];
    const float* iw2 = (const float*)d_in[7],  *ib2 = (const float*)d_in[8];
    const float* iw3 = (const float*)d_in[9],  *ib3 = (const float*)d_in[10];
    const float* aw1 = (const float*)d_in[11], *ab1 = (const float*)d_in[12];
    const float* aw2 = (const float*)d_in[13], *ab2 = (const float*)d_in[14];
    const float* aw3 = (const float*)d_in[15], *ab3 = (const float*)d_in[16];

    const int N = in_sizes[4];   // inv is [N]
    const int E = in_sizes[1];   // src is [E]

    ushort_t* featb  = (ushort_t*)d_ws;             // N*H bf16
    ushort_t* invb   = featb + (size_t)N * H;       // N*H bf16
    ushort_t* neighb = invb + (size_t)N * H;        // N*H bf16
    int* offsets = (int*)(neighb + (size_t)N * H);  // N+1
    unsigned* ebuf = (unsigned*)(offsets + (N + 1));
    int* packed  = (int*)(ebuf + E);
    ushort_t* frg = (ushort_t*)(packed + E);        // 80 frags x 512 us = 80 KB
    int* pbh     = (int*)(frg + 80 * 512);          // 256 x 256 partial hists
    int* cbase   = pbh + 256 * 256;                 // 257
    int* ccur    = cbase + 257;

    ushort_t* frg_inv = frg;
    ushort_t* frg_and = frg + 40 * 512;

    const int ntiles = (N + 15) / 16;
    const int NB     = (N + BSZ - 1) / BSZ;         // coarse buckets (<=256)
    const int cgrid  = (E + ACH - 1) / ACH;         // <=256 for E<=1M
    const int gp1    = (ntiles + 7) / 8;            // pass1: 4 waves x 2 tiles
    const int g45    = (ntiles + 7) / 8;            // mlp45: 4 waves x 2 tiles
    const int ggat   = (N + 15) / 16;               // gather: 4 waves x 4 nodes

    // 1) coarse histogram (per-block partials, no memset) || frag pre-pack
    prep_hist_k<<<cgrid + 20, 256, 0, stream>>>(dst, pbh, iw1, iw2, iw3,
                                                aw1, aw2, aw3, frg, E, cgrid);
    // 2) sum partials + exclusive scan
    cscan_k<<<1, 256, 0, stream>>>(pbh, cbase, ccur, NB, E, cgrid);
    // 3) coarse bin || pass1 MLP (independent; bin hides under the MLP)
    binp1_k<<<cgrid + gp1, 256, 0, stream>>>(src, dst, r, ccur, ebuf,
                                             feat, frg_inv, ib1, ib2, ib3,
                                             invb, featb, E, N, cgrid, ntiles);
    // 4) fine CSR build (offsets + packed)
    fine_k<<<NB, 256, 0, stream>>>(ebuf, cbase, offsets, packed, N, E, NB);
    // 5) neighb = bf16(mean of messages by dst)
    gather_mean_k<<<ggat, 256, 0, stream>>>(featb, invb, offsets,
                                            packed, neighb, N);
    // 6) fused: res = mlp_and(neighb); out = inv ? mlp_inv(res) : res
    mlp45_k<<<g45, 256, 0, stream>>>(neighb, frg_and, frg_inv,
                                     ab1, ab2, ab3, ib1, ib2, ib3,
                                     (float*)d_out, inv, N, ntiles);
}

// Round 20
// 124.550 us; speedup vs baseline: 1.1702x; 1.1702x over previous
//
#include <hip/hip_runtime.h>

// FuncConv: out = select(inv, mlp_inv(res), res); res = mlp_and(mean_dst(msg));
// msg = select(r, mlp_inv(feat[src]), feat[src]).
// R18: R17's cscan regression fix. R17 made cscan a 1-block 196-iteration
// serial sum (+12us). Now 1024-thr cscan: 4 row-groups x 256 cols, each
// thread sums ~49 strided rows (4 indep accumulators), LDS-reduce, then the
// 256-wide scan. All other kernels byte-identical to R17 (passed).
// Chain: prep_hist -> cscan -> {coarse_bin || pass1} -> fine -> gather -> mlp45.
//
// ws: featb[N*H bf16] invb[N*H bf16] neighb[N*H bf16]
//     offsets[N+1] ebuf[E] packed[E] frg[80*512 us] pbh[256*256] cbase[257] ccur[256]

#define H 128
#define HH 64
#define BSH 9     // log2 nodes per coarse bucket
#define BSZ 512   // nodes per coarse bucket
#define ACH 4096  // edges per coarse block

typedef float f32x4 __attribute__((ext_vector_type(4)));
typedef __bf16 bf16x8 __attribute__((ext_vector_type(8)));
typedef unsigned short us8 __attribute__((ext_vector_type(8)));
typedef unsigned short ushort_t;

__device__ __forceinline__ unsigned short bfbits(float f) {
    __bf16 h = (__bf16)f;                       // RNE convert
    return __builtin_bit_cast(unsigned short, h);
}
__device__ __forceinline__ bf16x8 as_bf16x8(us8 v) {
    return __builtin_bit_cast(bf16x8, v);
}
__device__ __forceinline__ float bfl(unsigned short u) {
    return __builtin_bit_cast(float, ((unsigned)u) << 16);
}

// transpose buffers, XOR-swizzled (byte ^= (row&7)<<4; 16B groups)
__device__ __forceinline__ int tb_off(int m, int j) {      // 16 x 64 bf16
    return m * 64 + ((((j * 2) ^ ((m & 7) << 4))) >> 1);
}
__device__ __forceinline__ int tb2_off(int m, int j) {     // 16 x 128 bf16
    return m * 128 + ((((j * 2) ^ ((m & 7) << 4))) >> 1);
}
__device__ __forceinline__ bf16x8 ld_tb(const unsigned short* tb, int m, int j0) {
    return as_bf16x8(*(const us8*)&tb[tb_off(m, j0)]);
}
__device__ __forceinline__ bf16x8 ld_tb2(const unsigned short* tb, int m, int j0) {
    return as_bf16x8(*(const us8*)&tb[tb2_off(m, j0)]);
}
// weight B-fragment from global (L1/L2-hot, 40KB working set per MLP)
__device__ __forceinline__ bf16x8 ld_frg(const ushort_t* __restrict__ FRG, int fid, int lane) {
    return as_bf16x8(*(const us8*)&FRG[(fid * 64 + lane) * 8]);
}

// ---------------- coarse dst-histogram (per-block partials) || frag pre-pack --
__global__ __launch_bounds__(256) void prep_hist_k(
    const int* __restrict__ dst, int* __restrict__ pbh,
    const float* __restrict__ iw1, const float* __restrict__ iw2,
    const float* __restrict__ iw3,
    const float* __restrict__ aw1, const float* __restrict__ aw2,
    const float* __restrict__ aw3,
    ushort_t* __restrict__ frg, int E, int cgrid)
{
    __shared__ int h[256];
    const int tid = threadIdx.x;
    if (blockIdx.x < cgrid) {
        h[tid] = 0;
        __syncthreads();
        const int base = blockIdx.x * ACH;
#pragma unroll
        for (int j = 0; j < 16; ++j) {
            const int e = base + j * 256 + tid;
            if (e < E) atomicAdd(&h[dst[e] >> BSH], 1);
        }
        __syncthreads();
        pbh[blockIdx.x * 256 + tid] = h[tid];     // plain store, no pre-zero
    } else {
        const int g = (blockIdx.x - cgrid) * 256 + tid;     // 80*64 = 5120
        const int fid2 = g >> 6;
        if (fid2 >= 80) return;
        const int lane = g & 63;
        const int ln = lane & 15, hi = lane >> 4;
        const int set = fid2 / 40;
        const int fid = fid2 - set * 40;
        const float* w; int inF, s, t;
        if (fid < 16)      { w = set ? aw1 : iw1; inF = H;  s = fid >> 2;        t = fid & 3; }
        else if (fid < 24) { w = set ? aw2 : iw2; inF = HH; s = (fid - 16) >> 2; t = (fid - 16) & 3; }
        else               { w = set ? aw3 : iw3; inF = HH; s = (fid - 24) >> 3; t = (fid - 24) & 7; }
        const float* p = w + (size_t)(t * 16 + ln) * inF + (s * 32 + hi * 8);
        f32x4 a = *(const f32x4*)p;
        f32x4 b = *(const f32x4*)(p + 4);
        ushort_t* d = &frg[(size_t)(fid2 * 64 + lane) * 8];
        d[0] = bfbits(a[0]); d[1] = bfbits(a[1]); d[2] = bfbits(a[2]); d[3] = bfbits(a[3]);
        d[4] = bfbits(b[0]); d[5] = bfbits(b[1]); d[6] = bfbits(b[2]); d[7] = bfbits(b[3]);
    }
}

// single block, 1024 threads: parallel partial-sum + exclusive scan -> cbase/ccur
__global__ __launch_bounds__(1024) void cscan_k(
    const int* __restrict__ pbh, int* __restrict__ cbase, int* __restrict__ ccur,
    int nb, int E, int cgrid)
{
    __shared__ int part[4][256];
    __shared__ int s[256];
    const int tid = threadIdx.x;
    const int col = tid & 255;
    const int grp = tid >> 8;                     // 0..3
    int a0 = 0, a1 = 0, a2 = 0, a3 = 0;
    int b = grp;
    for (; b + 12 < cgrid; b += 16) {             // 4 indep load chains
        a0 += pbh[(b)      * 256 + col];
        a1 += pbh[(b + 4)  * 256 + col];
        a2 += pbh[(b + 8)  * 256 + col];
        a3 += pbh[(b + 12) * 256 + col];
    }
    for (; b < cgrid; b += 4) a0 += pbh[b * 256 + col];
    part[grp][col] = (a0 + a1) + (a2 + a3);
    __syncthreads();
    int v = 0;
    if (tid < 256) {
        v = part[0][tid] + part[1][tid] + part[2][tid] + part[3][tid];
        if (tid >= nb) v = 0;
        s[tid] = v;
    }
    __syncthreads();
    for (int st = 1; st < 256; st <<= 1) {
        int t = (tid < 256 && tid >= st) ? s[tid - st] : 0;
        __syncthreads();
        if (tid < 256) s[tid] += t;
        __syncthreads();
    }
    if (tid < 256) {
        const int excl = s[tid] - v;
        if (tid < nb) { cbase[tid] = excl; ccur[tid] = excl; }
        if (tid == 0) cbase[nb] = E;
    }
}

// ---------------- fused: coarse bin || MLP pass 1 (bodies = R16/R17) ----------
__global__ __launch_bounds__(256) void binp1_k(
    const int* __restrict__ src, const int* __restrict__ dst,
    const int* __restrict__ r,
    int* __restrict__ ccur, unsigned* __restrict__ ebuf,
    const float* __restrict__ X,
    const ushort_t* __restrict__ FRG,
    const float* __restrict__ B1, const float* __restrict__ B2,
    const float* __restrict__ B3,
    ushort_t* __restrict__ invb, ushort_t* __restrict__ featb,
    int E, int N, int cgrid, int ntiles)
{
    __shared__ __align__(16) unsigned short TBs[4 * 2 * 16 * 64];  // 16 KB
    const int tid = threadIdx.x;

    if (blockIdx.x < cgrid) {
        int* hcnt  = (int*)TBs;           // 256
        int* gbase = hcnt + 256;          // 256
        int* lcur  = gbase + 256;         // 256
        hcnt[tid] = 0;
        __syncthreads();
        const int base = blockIdx.x * ACH;
        unsigned v[16]; int bk[16];
#pragma unroll
        for (int j = 0; j < 16; ++j) {
            const int e = base + j * 256 + tid;
            if (e < E) {
                const int d = dst[e];
                bk[j] = d >> BSH;
                v[j] = ((unsigned)(d & (BSZ - 1)) << 18) |
                       ((unsigned)src[e] << 1) | (unsigned)r[e];
                atomicAdd(&hcnt[bk[j]], 1);
            } else bk[j] = -1;
        }
        __syncthreads();
        const int c = hcnt[tid];
        gbase[tid] = (c > 0) ? atomicAdd(&ccur[tid], c) : 0;
        lcur[tid] = 0;
        __syncthreads();
#pragma unroll
        for (int j = 0; j < 16; ++j) {
            if (bk[j] >= 0) {
                const int loc = atomicAdd(&lcur[bk[j]], 1);
                ebuf[gbase[bk[j]] + loc] = v[j];
            }
        }
        return;
    }

    // ------- MLP pass-1 body: 4 waves x 2 tiles, shared frag loads -----------
    const int wv   = tid >> 6;
    const int lane = tid & 63;
    const int ln   = lane & 15;
    const int hi   = lane >> 4;

    const int gw = (blockIdx.x - cgrid) * 4 + wv;
    const int t0 = gw * 2;
    if (t0 >= ntiles) return;
    const bool hasB = (t0 + 1) < ntiles;
    const int node0A = t0 * 16;
    const int node0B = hasB ? (t0 + 1) * 16 : node0A;

    float b1r[4], b2r[4], b3r[8];
#pragma unroll
    for (int t = 0; t < 4; ++t) b1r[t] = B1[t * 16 + ln];
#pragma unroll
    for (int t = 0; t < 4; ++t) b2r[t] = B2[t * 16 + ln];
#pragma unroll
    for (int t = 0; t < 8; ++t) b3r[t] = B3[t * 16 + ln];

    unsigned short* tbA = &TBs[(wv * 2) * 16 * 64];
    unsigned short* tbB = tbA + 16 * 64;

    const size_t roA = (size_t)min(node0A + ln, N - 1) * H;
    const size_t roB = (size_t)min(node0B + ln, N - 1) * H;

    bf16x8 aA[4], aB[4];
#pragma unroll
    for (int s = 0; s < 4; ++s) {
        {
            f32x4 u = *(const f32x4*)(X + roA + s * 32 + hi * 8);
            f32x4 v = *(const f32x4*)(X + roA + s * 32 + hi * 8 + 4);
            bf16x8 f;
            f[0] = (__bf16)u[0]; f[1] = (__bf16)u[1]; f[2] = (__bf16)u[2]; f[3] = (__bf16)u[3];
            f[4] = (__bf16)v[0]; f[5] = (__bf16)v[1]; f[6] = (__bf16)v[2]; f[7] = (__bf16)v[3];
            aA[s] = f;
            *(us8*)(featb + roA + s * 32 + hi * 8) = __builtin_bit_cast(us8, f);
        }
        {
            f32x4 u = *(const f32x4*)(X + roB + s * 32 + hi * 8);
            f32x4 v = *(const f32x4*)(X + roB + s * 32 + hi * 8 + 4);
            bf16x8 f;
            f[0] = (__bf16)u[0]; f[1] = (__bf16)u[1]; f[2] = (__bf16)u[2]; f[3] = (__bf16)u[3];
            f[4] = (__bf16)v[0]; f[5] = (__bf16)v[1]; f[6] = (__bf16)v[2]; f[7] = (__bf16)v[3];
            aB[s] = f;
            if (hasB) *(us8*)(featb + roB + s * 32 + hi * 8) = __builtin_bit_cast(us8, f);
        }
    }

#pragma unroll 4
    for (int t = 0; t < 4; ++t) {
        f32x4 accA = {0.f, 0.f, 0.f, 0.f}, accB = {0.f, 0.f, 0.f, 0.f};
#pragma unroll
        for (int s = 0; s < 4; ++s) {
            const bf16x8 f = ld_frg(FRG, s * 4 + t, lane);
            accA = __builtin_amdgcn_mfma_f32_16x16x32_bf16(aA[s], f, accA, 0, 0, 0);
            accB = __builtin_amdgcn_mfma_f32_16x16x32_bf16(aB[s], f, accB, 0, 0, 0);
        }
#pragma unroll
        for (int q = 0; q < 4; ++q) {
            float yA = accA[q] + b1r[t];
            yA = (yA >= 0.f) ? yA : 0.01f * yA;
            tbA[tb_off(hi * 4 + q, t * 16 + ln)] = bfbits(yA);
            float yB = accB[q] + b1r[t];
            yB = (yB >= 0.f) ? yB : 0.01f * yB;
            tbB[tb_off(hi * 4 + q, t * 16 + ln)] = bfbits(yB);
        }
    }

    bf16x8 a2A[2], a2B[2];
#pragma unroll
    for (int s = 0; s < 2; ++s) {
        a2A[s] = ld_tb(tbA, ln, s * 32 + hi * 8);
        a2B[s] = ld_tb(tbB, ln, s * 32 + hi * 8);
    }
#pragma unroll 4
    for (int t = 0; t < 4; ++t) {
        f32x4 accA = {0.f, 0.f, 0.f, 0.f}, accB = {0.f, 0.f, 0.f, 0.f};
#pragma unroll
        for (int s = 0; s < 2; ++s) {
            const bf16x8 f = ld_frg(FRG, 16 + s * 4 + t, lane);
            accA = __builtin_amdgcn_mfma_f32_16x16x32_bf16(a2A[s], f, accA, 0, 0, 0);
            accB = __builtin_amdgcn_mfma_f32_16x16x32_bf16(a2B[s], f, accB, 0, 0, 0);
        }
#pragma unroll
        for (int q = 0; q < 4; ++q) {
            float yA = accA[q] + b2r[t];
            yA = (yA >= 0.f) ? yA : 0.01f * yA;
            tbA[tb_off(hi * 4 + q, t * 16 + ln)] = bfbits(yA);
            float yB = accB[q] + b2r[t];
            yB = (yB >= 0.f) ? yB : 0.01f * yB;
            tbB[tb_off(hi * 4 + q, t * 16 + ln)] = bfbits(yB);
        }
    }

    bf16x8 a3A[2], a3B[2];
#pragma unroll
    for (int s = 0; s < 2; ++s) {
        a3A[s] = ld_tb(tbA, ln, s * 32 + hi * 8);
        a3B[s] = ld_tb(tbB, ln, s * 32 + hi * 8);
    }
#pragma unroll
    for (int half = 0; half < 2; ++half) {
#pragma unroll 2
        for (int t2 = 0; t2 < 4; ++t2) {
            const int t = half * 4 + t2;
            f32x4 accA = {0.f, 0.f, 0.f, 0.f}, accB = {0.f, 0.f, 0.f, 0.f};
#pragma unroll
            for (int s = 0; s < 2; ++s) {
                const bf16x8 f = ld_frg(FRG, 24 + s * 8 + t, lane);
                accA = __builtin_amdgcn_mfma_f32_16x16x32_bf16(a3A[s], f, accA, 0, 0, 0);
                accB = __builtin_amdgcn_mfma_f32_16x16x32_bf16(a3B[s], f, accB, 0, 0, 0);
            }
#pragma unroll
            for (int q = 0; q < 4; ++q) {
                tbA[tb_off(hi * 4 + q, t2 * 16 + ln)] = bfbits(accA[q] + b3r[t]);
                tbB[tb_off(hi * 4 + q, t2 * 16 + ln)] = bfbits(accB[q] + b3r[t]);
            }
        }
        const int rr = lane >> 2, c0 = (lane & 3) * 16;
        if (node0A + rr < N) {
            us8 w0 = __builtin_bit_cast(us8, ld_tb(tbA, rr, c0));
            us8 w1 = __builtin_bit_cast(us8, ld_tb(tbA, rr, c0 + 8));
            ushort_t* op = invb + (size_t)(node0A + rr) * H + half * 64 + c0;
            *(us8*)op = w0;
            *(us8*)(op + 8) = w1;
        }
        if (hasB && node0B + rr < N) {
            us8 w0 = __builtin_bit_cast(us8, ld_tb(tbB, rr, c0));
            us8 w1 = __builtin_bit_cast(us8, ld_tb(tbB, rr, c0 + 8));
            ushort_t* op = invb + (size_t)(node0B + rr) * H + half * 64 + c0;
            *(us8*)op = w0;
            *(us8*)(op + 8) = w1;
        }
    }
}

// ---------------- fine CSR build (standalone, 256 thr, pair-scan) -------------
__global__ __launch_bounds__(256) void fine_k(
    const unsigned* __restrict__ ebuf, const int* __restrict__ cbase,
    int* __restrict__ offsets, int* __restrict__ packed, int N, int E, int NB)
{
    __shared__ int lcur[BSZ];
    __shared__ int ps[256];
    const int tid = threadIdx.x;
    const int b = blockIdx.x;
    const int lo = b << BSH;
    const int nn = min(BSZ, N - lo);
    const int rstart = cbase[b];
    const int rend   = cbase[b + 1];
    lcur[tid] = 0; lcur[tid + 256] = 0;
    __syncthreads();
    for (int i = rstart + tid; i < rend; i += 256)
        atomicAdd(&lcur[ebuf[i] >> 18], 1);
    __syncthreads();
    const int v0 = lcur[2 * tid];
    const int v1 = lcur[2 * tid + 1];
    const int psum = v0 + v1;
    ps[tid] = psum;
    __syncthreads();
    for (int st = 1; st < 256; st <<= 1) {
        int t = (tid >= st) ? ps[tid - st] : 0;
        __syncthreads();
        ps[tid] += t;
        __syncthreads();
    }
    const int e0 = rstart + ps[tid] - psum;     // exclusive prefix
    const int e1 = e0 + v0;
    if (2 * tid < nn)     offsets[lo + 2 * tid] = e0;
    if (2 * tid + 1 < nn) offsets[lo + 2 * tid + 1] = e1;
    if (b == NB - 1 && tid == 0) offsets[N] = E;
    __syncthreads();
    lcur[2 * tid] = e0;
    lcur[2 * tid + 1] = e1;
    __syncthreads();
    for (int i = rstart + tid; i < rend; i += 256) {
        const unsigned w = ebuf[i];
        const int dloc = w >> 18;
        const int pos = atomicAdd(&lcur[dloc], 1);
        packed[pos] = (int)(((w & 0x3ffffu) >> 1) | ((w & 1u) << 31));
    }
}

// 4 nodes per wave (16 lanes each = full 128-col row); 8-deep edge unroll (R12)
__global__ __launch_bounds__(256) void gather_mean_k(
    const ushort_t* __restrict__ featb, const ushort_t* __restrict__ invb,
    const int* __restrict__ offsets,
    const int* __restrict__ packed, ushort_t* __restrict__ neighb, int N)
{
    const int wv = threadIdx.x >> 6, lane = threadIdx.x & 63;
    const int n0 = (blockIdx.x * 4 + wv) * 4;
    if (n0 >= N) return;
    const int g = lane >> 4;                      // node-in-wave 0..3
    const int nid = n0 + g;
    const bool act = nid < N;
    const int n = min(nid, N - 1);
    const int start = offsets[n];
    const int d = offsets[n + 1] - start;
    const size_t co = (size_t)(lane & 15) * 8;    // col base (8 bf16 = 16B)
    float a[8] = {0.f, 0.f, 0.f, 0.f, 0.f, 0.f, 0.f, 0.f};
    int k = 0;
    for (; k + 7 < d; k += 8) {                   // 8 rows in flight
        int p[8];
#pragma unroll
        for (int j = 0; j < 8; ++j) p[j] = packed[start + k + j];
        us8 u[8];
#pragma unroll
        for (int j = 0; j < 8; ++j) {
            const ushort_t* t = (p[j] < 0) ? invb : featb;
            u[j] = *(const us8*)(t + (size_t)(p[j] & 0x7fffffff) * H + co);
        }
#pragma unroll
        for (int j = 0; j < 8; ++j)
#pragma unroll
            for (int i = 0; i < 8; ++i) a[i] += bfl(u[j][i]);
    }
    if (k + 3 < d) {                              // 4 rows in flight
        int p[4];
#pragma unroll
        for (int j = 0; j < 4; ++j) p[j] = packed[start + k + j];
        us8 u[4];
#pragma unroll
        for (int j = 0; j < 4; ++j) {
            const ushort_t* t = (p[j] < 0) ? invb : featb;
            u[j] = *(const us8*)(t + (size_t)(p[j] & 0x7fffffff) * H + co);
        }
#pragma unroll
        for (int j = 0; j < 4; ++j)
#pragma unroll
            for (int i = 0; i < 8; ++i) a[i] += bfl(u[j][i]);
        k += 4;
    }
    for (; k < d; ++k) {                          // <=3 rows tail
        const int p = packed[start + k];
        const ushort_t* t = (p < 0) ? invb : featb;
        const us8 u = *(const us8*)(t + (size_t)(p & 0x7fffffff) * H + co);
#pragma unroll
        for (int i = 0; i < 8; ++i) a[i] += bfl(u[i]);
    }
    if (act) {
        const float scl = 1.0f / (float)max(d, 1);
        us8 o;
#pragma unroll
        for (int i = 0; i < 8; ++i) o[i] = bfbits(a[i] * scl);
        *(us8*)(neighb + (size_t)n * H + co) = o;
    }
}

// ---------------- fused pass 4+5, 2 tiles per wave (R9/R12) -------------------
__global__ __launch_bounds__(256) void mlp45_k(
    const ushort_t* __restrict__ Xb,          // neighb, bf16
    const ushort_t* __restrict__ FRGa,        // and frags
    const ushort_t* __restrict__ FRGi,        // inv frags
    const float* __restrict__ A1, const float* __restrict__ A2,
    const float* __restrict__ A3,
    const float* __restrict__ I1, const float* __restrict__ I2,
    const float* __restrict__ I3,
    float* __restrict__ OUT,
    const int* __restrict__ invp,
    int nrows, int ntiles)
{
    __shared__ __align__(16) unsigned short TB2[4 * 2 * 16 * 128];  // 32 KB
    const int tid  = threadIdx.x;
    const int wv   = tid >> 6;
    const int lane = tid & 63;
    const int ln   = lane & 15;
    const int hi   = lane >> 4;

    const int gw = blockIdx.x * 4 + wv;
    const int t0 = gw * 2;
    if (t0 >= ntiles) return;
    const bool hasB = (t0 + 1) < ntiles;
    const int node0A = t0 * 16;
    const int node0B = hasB ? (t0 + 1) * 16 : node0A;

    unsigned short* tbA = &TB2[(wv * 2) * 16 * 128];
    unsigned short* tbB = tbA + 16 * 128;

    int iqA[4], iqB[4];
#pragma unroll
    for (int q = 0; q < 4; ++q) {
        const int rA = node0A + hi * 4 + q;
        const int rB = node0B + hi * 4 + q;
        iqA[q] = (rA < nrows) ? invp[rA] : 1;
        iqB[q] = (rB < nrows) ? invp[rB] : 1;
    }

    // ---- phase A: mlp_and ----
    {
        float b1r[4], b2r[4], b3r[8];
#pragma unroll
        for (int t = 0; t < 4; ++t) b1r[t] = A1[t * 16 + ln];
#pragma unroll
        for (int t = 0; t < 4; ++t) b2r[t] = A2[t * 16 + ln];
#pragma unroll
        for (int t = 0; t < 8; ++t) b3r[t] = A3[t * 16 + ln];

        const size_t roA = (size_t)min(node0A + ln, nrows - 1) * H;
        const size_t roB = (size_t)min(node0B + ln, nrows - 1) * H;
        bf16x8 aA[4], aB[4];
#pragma unroll
        for (int s = 0; s < 4; ++s) {
            aA[s] = as_bf16x8(*(const us8*)(Xb + roA + s * 32 + hi * 8));
            aB[s] = as_bf16x8(*(const us8*)(Xb + roB + s * 32 + hi * 8));
        }

#pragma unroll 2
        for (int t = 0; t < 4; ++t) {
            f32x4 accA = {0.f, 0.f, 0.f, 0.f}, accB = {0.f, 0.f, 0.f, 0.f};
#pragma unroll
            for (int s = 0; s < 4; ++s) {
                const bf16x8 f = ld_frg(FRGa, s * 4 + t, lane);
                accA = __builtin_amdgcn_mfma_f32_16x16x32_bf16(aA[s], f, accA, 0, 0, 0);
                accB = __builtin_amdgcn_mfma_f32_16x16x32_bf16(aB[s], f, accB, 0, 0, 0);
            }
#pragma unroll
            for (int q = 0; q < 4; ++q) {
                float yA = accA[q] + b1r[t];
                yA = (yA >= 0.f) ? yA : 0.01f * yA;
                tbA[tb2_off(hi * 4 + q, t * 16 + ln)] = bfbits(yA);
                float yB = accB[q] + b1r[t];
                yB = (yB >= 0.f) ? yB : 0.01f * yB;
                tbB[tb2_off(hi * 4 + q, t * 16 + ln)] = bfbits(yB);
            }
        }

        bf16x8 a2A[2], a2B[2];
#pragma unroll
        for (int s = 0; s < 2; ++s) {
            a2A[s] = ld_tb2(tbA, ln, s * 32 + hi * 8);
            a2B[s] = ld_tb2(tbB, ln, s * 32 + hi * 8);
        }
#pragma unroll 2
        for (int t = 0; t < 4; ++t) {
            f32x4 accA = {0.f, 0.f, 0.f, 0.f}, accB = {0.f, 0.f, 0.f, 0.f};
#pragma unroll
            for (int s = 0; s < 2; ++s) {
                const bf16x8 f = ld_frg(FRGa, 16 + s * 4 + t, lane);
                accA = __builtin_amdgcn_mfma_f32_16x16x32_bf16(a2A[s], f, accA, 0, 0, 0);
                accB = __builtin_amdgcn_mfma_f32_16x16x32_bf16(a2B[s], f, accB, 0, 0, 0);
            }
#pragma unroll
            for (int q = 0; q < 4; ++q) {
                float yA = accA[q] + b2r[t];
                yA = (yA >= 0.f) ? yA : 0.01f * yA;
                tbA[tb2_off(hi * 4 + q, t * 16 + ln)] = bfbits(yA);
                float yB = accB[q] + b2r[t];
                yB = (yB >= 0.f) ? yB : 0.01f * yB;
                tbB[tb2_off(hi * 4 + q, t * 16 + ln)] = bfbits(yB);
            }
        }

        bf16x8 a3A[2], a3B[2];
#pragma unroll
        for (int s = 0; s < 2; ++s) {
            a3A[s] = ld_tb2(tbA, ln, s * 32 + hi * 8);
            a3B[s] = ld_tb2(tbB, ln, s * 32 + hi * 8);
        }
#pragma unroll 2
        for (int t = 0; t < 8; ++t) {
            f32x4 accA = {0.f, 0.f, 0.f, 0.f}, accB = {0.f, 0.f, 0.f, 0.f};
#pragma unroll
            for (int s = 0; s < 2; ++s) {
                const bf16x8 f = ld_frg(FRGa, 24 + s * 8 + t, lane);
                accA = __builtin_amdgcn_mfma_f32_16x16x32_bf16(a3A[s], f, accA, 0, 0, 0);
                accB = __builtin_amdgcn_mfma_f32_16x16x32_bf16(a3B[s], f, accB, 0, 0, 0);
            }
#pragma unroll
            for (int q = 0; q < 4; ++q) {
                const float yA = accA[q] + b3r[t];
                tbA[tb2_off(hi * 4 + q, t * 16 + ln)] = bfbits(yA);
                const int rA = node0A + hi * 4 + q;
                if (rA < nrows && !iqA[q])
                    OUT[(size_t)rA * H + t * 16 + ln] = yA;
                const float yB = accB[q] + b3r[t];
                tbB[tb2_off(hi * 4 + q, t * 16 + ln)] = bfbits(yB);
                const int rB = node0B + hi * 4 + q;
                if (hasB && rB < nrows && !iqB[q])
                    OUT[(size_t)rB * H + t * 16 + ln] = yB;
            }
        }
    }

    // ---- phase B: mlp_inv(res) for inv rows ----
    {
        float b1r[4], b2r[4], b3r[8];
#pragma unroll
        for (int t = 0; t < 4; ++t) b1r[t] = I1[t * 16 + ln];
#pragma unroll
        for (int t = 0; t < 4; ++t) b2r[t] = I2[t * 16 + ln];
#pragma unroll
        for (int t = 0; t < 8; ++t) b3r[t] = I3[t * 16 + ln];

        bf16x8 aA[4], aB[4];
#pragma unroll
        for (int s = 0; s < 4; ++s) {
            aA[s] = ld_tb2(tbA, ln, s * 32 + hi * 8);   // reads drain before writes
            aB[s] = ld_tb2(tbB, ln, s * 32 + hi * 8);
        }

#pragma unroll 2
        for (int t = 0; t < 4; ++t) {
            f32x4 accA = {0.f, 0.f, 0.f, 0.f}, accB = {0.f, 0.f, 0.f, 0.f};
#pragma unroll
            for (int s = 0; s < 4; ++s) {
                const bf16x8 f = ld_frg(FRGi, s * 4 + t, lane);
                accA = __builtin_amdgcn_mfma_f32_16x16x32_bf16(aA[s], f, accA, 0, 0, 0);
                accB = __builtin_amdgcn_mfma_f32_16x16x32_bf16(aB[s], f, accB, 0, 0, 0);
            }
#pragma unroll
            for (int q = 0; q < 4; ++q) {
                float yA = accA[q] + b1r[t];
                yA = (yA >= 0.f) ? yA : 0.01f * yA;
                tbA[tb2_off(hi * 4 + q, t * 16 + ln)] = bfbits(yA);
                float yB = accB[q] + b1r[t];
                yB = (yB >= 0.f) ? yB : 0.01f * yB;
                tbB[tb2_off(hi * 4 + q, t * 16 + ln)] = bfbits(yB);
            }
        }

        bf16x8 a2A[2], a2B[2];
#pragma unroll
        for (int s = 0; s < 2; ++s) {
            a2A[s] = ld_tb2(tbA, ln, s * 32 + hi * 8);
            a2B[s] = ld_tb2(tbB, ln, s * 32 + hi * 8);
        }
#pragma unroll 2
        for (int t = 0; t < 4; ++t) {
            f32x4 accA = {0.f, 0.f, 0.f, 0.f}, accB = {0.f, 0.f, 0.f, 0.f};
#pragma unroll
            for (int s = 0; s < 2; ++s) {
                const bf16x8 f = ld_frg(FRGi, 16 + s * 4 + t, lane);
                accA = __builtin_amdgcn_mfma_f32_16x16x32_bf16(a2A[s], f, accA, 0, 0, 0);
                accB = __builtin_amdgcn_mfma_f32_16x16x32_bf16(a2B[s], f, accB, 0, 0, 0);
            }
#pragma unroll
            for (int q = 0; q < 4; ++q) {
                float yA = accA[q] + b2r[t];
                yA = (yA >= 0.f) ? yA : 0.01f * yA;
                tbA[tb2_off(hi * 4 + q, t * 16 + ln)] = bfbits(yA);
                float yB = accB[q] + b2r[t];
                yB = (yB >= 0.f) ? yB : 0.01f * yB;
                tbB[tb2_off(hi * 4 + q, t * 16 + ln)] = bfbits(yB);
            }
        }

        bf16x8 a3A[2], a3B[2];
#pragma unroll
        for (int s = 0; s < 2; ++s) {
            a3A[s] = ld_tb2(tbA, ln, s * 32 + hi * 8);
            a3B[s] = ld_tb2(tbB, ln, s * 32 + hi * 8);
        }
#pragma unroll 2
        for (int t = 0; t < 8; ++t) {
            f32x4 accA = {0.f, 0.f, 0.f, 0.f}, accB = {0.f, 0.f, 0.f, 0.f};
#pragma unroll
            for (int s = 0; s < 2; ++s) {
                const bf16x8 f = ld_frg(FRGi, 24 + s * 8 + t, lane);
                accA = __builtin_amdgcn_mfma_f32_16x16x32_bf16(a3A[s], f, accA, 0, 0, 0);
                accB = __builtin_amdgcn_mfma_f32_16x16x32_bf16(a3B[s], f, accB, 0, 0, 0);
            }
#pragma unroll
            for (int q = 0; q < 4; ++q) {
                const int rA = node0A + hi * 4 + q;
                if (rA < nrows && iqA[q])
                    OUT[(size_t)rA * H + t * 16 + ln] = accA[q] + b3r[t];
                const int rB = node0B + hi * 4 + q;
                if (hasB && rB < nrows && iqB[q])
                    OUT[(size_t)rB * H + t * 16 + ln] = accB[q] + b3r[t];
            }
        }
    }
}

extern "C" void kernel_launch(void* const* d_in, const int* in_sizes, int n_in,
                              void* d_out, int out_size, void* d_ws, size_t ws_size,
                              hipStream_t stream) {
    const float* feat = (const float*)d_in[0];
    const int*   src  = (const int*)d_in[1];
    const int*   dst  = (const int*)d_in[2];
    const int*   r    = (const int*)d_in[3];
    const int*   inv  = (const int*)d_in[4];
    const float* iw1 = (const float*)d_in[5],  *ib1 = (const float*)d_in[6];
    const float* iw2 = (const float*)d_in[7],  *ib2 = (const float*)d_in[8];
    const float* iw3 = (const float*)d_in[9],  *ib3 = (const float*)d_in[10];
    const float* aw1 = (const float*)d_in[11], *ab1 = (const float*)d_in[12];
    const float* aw2 = (const float*)d_in[13], *ab2 = (const float*)d_in[14];
    const float* aw3 = (const float*)d_in[15], *ab3 = (const float*)d_in[16];

    const int N = in_sizes[4];   // inv is [N]
    const int E = in_sizes[1];   // src is [E]

    ushort_t* featb  = (ushort_t*)d_ws;             // N*H bf16
    ushort_t* invb   = featb + (size_t)N * H;       // N*H bf16
    ushort_t* neighb = invb + (size_t)N * H;        // N*H bf16
    int* offsets = (int*)(neighb + (size_t)N * H);  // N+1
    unsigned* ebuf = (unsigned*)(offsets + (N + 1));
    int* packed  = (int*)(ebuf + E);
    ushort_t* frg = (ushort_t*)(packed + E);        // 80 frags x 512 us = 80 KB
    int* pbh     = (int*)(frg + 80 * 512);          // 256 x 256 partial hists
    int* cbase   = pbh + 256 * 256;                 // 257
    int* ccur    = cbase + 257;

    ushort_t* frg_inv = frg;
    ushort_t* frg_and = frg + 40 * 512;

    const int ntiles = (N + 15) / 16;
    const int NB     = (N + BSZ - 1) / BSZ;         // coarse buckets (<=256)
    const int cgrid  = (E + ACH - 1) / ACH;         // <=256 for E<=1M
    const int gp1    = (ntiles + 7) / 8;            // pass1: 4 waves x 2 tiles
    const int g45    = (ntiles + 7) / 8;            // mlp45: 4 waves x 2 tiles
    const int ggat   = (N + 15) / 16;               // gather: 4 waves x 4 nodes

    // 1) coarse histogram (per-block partials, no memset) || frag pre-pack
    prep_hist_k<<<cgrid + 20, 256, 0, stream>>>(dst, pbh, iw1, iw2, iw3,
                                                aw1, aw2, aw3, frg, E, cgrid);
    // 2) parallel partial-sum + exclusive scan
    cscan_k<<<1, 1024, 0, stream>>>(pbh, cbase, ccur, NB, E, cgrid);
    // 3) coarse bin || pass1 MLP (independent; bin hides under the MLP)
    binp1_k<<<cgrid + gp1, 256, 0, stream>>>(src, dst, r, ccur, ebuf,
                                             feat, frg_inv, ib1, ib2, ib3,
                                             invb, featb, E, N, cgrid, ntiles);
    // 4) fine CSR build (offsets + packed)
    fine_k<<<NB, 256, 0, stream>>>(ebuf, cbase, offsets, packed, N, E, NB);
    // 5) neighb = bf16(mean of messages by dst)
    gather_mean_k<<<ggat, 256, 0, stream>>>(featb, invb, offsets,
                                            packed, neighb, N);
    // 6) fused: res = mlp_and(neighb); out = inv ? mlp_inv(res) : res
    mlp45_k<<<g45, 256, 0, stream>>>(neighb, frg_and, frg_inv,
                                     ab1, ab2, ab3, ib1, ib2, ib3,
                                     (float*)d_out, inv, N, ntiles);
}